// Round 1
// baseline (1848.915 us; speedup 1.0000x reference)
//
#include <hip/hip_runtime.h>

// Fused implementation of the whole network, one workgroup per batch sample.
// All conv/lin chains between ReLUs are re-associated into cheapest order
// (lin and conv commute: lin contracts the last axis, conv is pointwise in it).
// Derived bias constants (row-sums of lin weights) are computed per-WG in S0.

struct Params {
  const float* x;
  const float* ca1_w; const float* ca1_b;
  const float* l01_w; const float* l01_b;
  const float* cb1_w; const float* cb1_b;
  const float* cc1_w; const float* cc1_b;
  const float* r01_w; const float* r01_b;
  const float* c1_w;  const float* c1_b;
  const float* l1_w;  const float* l1_b;
  const float* c2_w;  const float* c2_b;
  const float* ca_w;  const float* ca_b;
  const float* ra_w;  const float* ra_b;
  const float* ca2_w; const float* ca2_b;
  const float* l02_w; const float* l02_b;
  const float* cb2_w; const float* cb2_b;
  const float* cc2_w; const float* cc2_b;
  const float* r02_w; const float* r02_b;
  const float* fl_w;  const float* fl_b;
  float* out;
};

// LDS layout (floats), total 19927 (79708 B) -> 2 WG/CU (159416 <= 163840)
//  region A (0..7500): stage-A scratch, later reused as W[125][3][20]
//  v   @ 7500 : [25][5][60]  (stacked l1|ra applied to x1, no lin bias)
//  t   @15000 : [75][4][8]   (j-chunk of block-B z, rows padded to 8)
//              later reused: zC[25][2][10] @15000, zCb @15600, yC2 @15610
//  x2c @17400 : [125][3][6]
//  consts @19650 : S01[81] S1[30] SR[30] SAc[125] S02[10] Scc2[1]

__global__ __launch_bounds__(256, 2)
void fused_renet(Params P) {
  __shared__ float lds[19927];
  const int tid = threadIdx.x;
  const int b = blockIdx.x;

  float* xs   = lds + 0;      // 635   x[5][127]
  float* XLp  = lds + 635;    // 567   l01(x), h-padded rows 0..6
  float* yA   = lds + 1202;   // 405   r01(x)+r01_b
  float* zA   = lds + 1607;   // 2025  relu block-A z  [5][5][81]
  float* Pp   = lds + 3632;   // 2100  SW*zA, h-padded [5][7][60]
  float* Q    = lds + 5732;   // 300   SW*yA [5][60]
  float* W    = lds + 0;      // 7500  (reuses region A)
  float* v    = lds + 7500;   // 7500
  float* t    = lds + 15000;  // 2400
  float* zC   = lds + 15000;  // 500 (reuses t)
  float* zCb  = lds + 15600;  // 10
  float* yC2  = lds + 15610;  // 30
  float* x2c  = lds + 17400;  // 2250
  float* cS01 = lds + 19650;  // 81
  float* cS1  = lds + 19731;  // 30
  float* cSR  = lds + 19761;  // 30
  float* cSAc = lds + 19791;  // 125
  float* cS02 = lds + 19916;  // 10
  float* cScc2= lds + 19926;  // 1

  // ---- S0: load x, zero pads, derived constants ----
  const float* xg = P.x + b * 635;
  for (int k = tid; k < 635; k += 256) xs[k] = xg[k];
  for (int k = tid; k < 600; k += 256) {          // Pp pad rows 0 and 6
    int c5 = k / 120, r = k % 120;
    int hp = (r / 60) * 6, j2 = r % 60;
    Pp[c5 * 420 + hp * 60 + j2] = 0.f;
  }
  for (int k = tid; k < 162; k += 256) {          // XLp pad rows 0 and 6
    int h6 = (k / 81) * 6, a = k % 81;
    XLp[h6 * 81 + a] = 0.f;
  }
  for (int k = tid; k < 277; k += 256) {          // weight row-sums
    float s = 0.f;
    if (k < 81)       { for (int i = 0; i < 127; ++i) s += P.l01_w[k * 127 + i]; cS01[k] = s; }
    else if (k < 111) { int j = k - 81;  for (int a = 0; a < 81; ++a) s += P.l1_w[j * 81 + a]; cS1[j] = s; }
    else if (k < 141) { int j = k - 111; for (int a = 0; a < 81; ++a) s += P.ra_w[j * 81 + a]; cSR[j] = s; }
    else if (k < 266) { int o = k - 141; for (int i = 0; i < 75; ++i) s += P.ca_w[o * 75 + i]; cSAc[o] = s; }
    else if (k < 276) { int q = k - 266; for (int j = 0; j < 30; ++j) s += P.l02_w[q * 30 + j]; cS02[q] = s; }
    else              { for (int o = 0; o < 125; ++o) s += P.cc2_w[o]; cScc2[0] = s; }
  }
  __syncthreads();

  // ---- S1: XL = l01*x (no bias), yA = r01*x + r01_b ----
  if (tid < 162) {
    const float* wr = (tid < 81) ? (P.l01_w + tid * 127) : (P.r01_w + (tid - 81) * 127);
    float a0 = 0, a1 = 0, a2 = 0, a3 = 0, a4 = 0;
    for (int i = 0; i < 127; ++i) {
      float wv = wr[i];
      a0 += wv * xs[i];       a1 += wv * xs[127 + i]; a2 += wv * xs[254 + i];
      a3 += wv * xs[381 + i]; a4 += wv * xs[508 + i];
    }
    if (tid < 81) {
      XLp[ 81 + tid] = a0; XLp[162 + tid] = a1; XLp[243 + tid] = a2;
      XLp[324 + tid] = a3; XLp[405 + tid] = a4;
    } else {
      int a = tid - 81; float rb = P.r01_b[a];
      yA[a] = a0 + rb; yA[81 + a] = a1 + rb; yA[162 + a] = a2 + rb;
      yA[243 + a] = a3 + rb; yA[324 + a] = a4 + rb;
    }
  }
  __syncthreads();

  // ---- S2: zA = relu(conv_ca1(XL) + ca1_b*S01 + l01_b) ----
  for (int k = tid; k < 2025; k += 256) {
    int c5 = k / 405, r = k % 405, h = r / 81, a = r % 81;
    float s = P.ca1_b[c5] * cS01[a] + P.l01_b[a];
    for (int dh = 0; dh < 3; ++dh) s += P.ca1_w[c5 * 3 + dh] * XLp[(h + dh) * 81 + a];
    zA[k] = fmaxf(s, 0.f);
  }
  __syncthreads();

  // ---- S3: P = SW*zA (h-padded), Q = SW*yA.  SW = [l1_w; ra_w] ----
  for (int k = tid; k < 1800; k += 256) {
    if (k < 1500) {
      int j2 = k / 25, ch = k % 25, c5 = ch / 5, h = ch % 5;
      const float* swr = (j2 < 30) ? (P.l1_w + j2 * 81) : (P.ra_w + (j2 - 30) * 81);
      const float* zr = zA + c5 * 405 + h * 81;
      float s = 0.f;
      for (int a = 0; a < 81; ++a) s += swr[a] * zr[a];
      Pp[c5 * 420 + (h + 1) * 60 + j2] = s;
    } else {
      int k2 = k - 1500, j2 = k2 / 5, h = k2 % 5;
      const float* swr = (j2 < 30) ? (P.l1_w + j2 * 81) : (P.ra_w + (j2 - 30) * 81);
      const float* yr = yA + h * 81;
      float s = 0.f;
      for (int a = 0; a < 81; ++a) s += swr[a] * yr[a];
      Q[h * 60 + j2] = s;
    }
  }
  __syncthreads();

  // ---- S4: v = SW*x1 = conv_cb1(P) + cc1_w*Q + (cb1_b+cc1_b)*rowsum(SW) ----
  for (int k = tid; k < 7500; k += 256) {
    int c = k / 300, r = k % 300, h = r / 60, j2 = r % 60;
    float s = P.cc1_w[c] * Q[h * 60 + j2]
            + (P.cb1_b[c] + P.cc1_b[c]) * (j2 < 30 ? cS1[j2] : cSR[j2 - 30]);
    const float* wb = P.cb1_w + c * 15;
    for (int c5 = 0; c5 < 5; ++c5)
      for (int dh = 0; dh < 3; ++dh)
        s += wb[c5 * 3 + dh] * Pp[c5 * 420 + (h + dh) * 60 + j2];
    v[k] = s;
  }
  __syncthreads();

  // ---- S6: block B + contraction into W (register accumulators), j-chunked ----
  float wacc[30];
#pragma unroll
  for (int kk = 0; kk < 30; ++kk) wacc[kk] = 0.f;

  for (int jc = 0; jc < 30; jc += 6) {
    // S6a: t = relu(conv_c1(VL) + c1_b*S1 + l1_b)
    for (int k = tid; k < 1800; k += 256) {
      int o = k / 24, r = k % 24, h = r / 6, j = r % 6, jj = jc + j;
      float s = P.c1_b[o] * cS1[jj] + P.l1_b[jj];
      const float* wb = P.c1_w + o * 50;
      const float* vb = v + h * 60 + jj;
      for (int c = 0; c < 25; ++c) {
        s += wb[c * 2 + 0] * vb[c * 300];
        s += wb[c * 2 + 1] * vb[c * 300 + 60];
      }
      t[o * 32 + h * 8 + j] = fmaxf(s, 0.f);
    }
    __syncthreads();

    // S6b1: x2 = conv_c2(t) + conv_ca(VR) + c2_b + ca_b + ra_b*rowsum(ca_w)
    for (int u = tid; u < 750; u += 256) {
      int o = u / 6, r = u % 6, h = r >> 1, g = r & 1, j0 = g * 3;
      float sac = cSAc[o];
      float base = P.c2_b[o] + P.ca_b[o];
      float acc0 = base + P.ra_b[jc + j0 + 0] * sac;
      float acc1 = base + P.ra_b[jc + j0 + 1] * sac;
      float acc2 = base + P.ra_b[jc + j0 + 2] * sac;
      const float* w2 = P.c2_w + o * 150;
      const float* tb = t + h * 8 + j0;
      for (int c = 0; c < 75; ++c) {
        float w0 = w2[c * 2], w1 = w2[c * 2 + 1];
        acc0 += w0 * tb[c * 32 + 0] + w1 * tb[c * 32 + 8];
        acc1 += w0 * tb[c * 32 + 1] + w1 * tb[c * 32 + 9];
        acc2 += w0 * tb[c * 32 + 2] + w1 * tb[c * 32 + 10];
      }
      const float* wa = P.ca_w + o * 75;
      const float* vb = v + h * 60 + 30 + jc + j0;
      for (int c = 0; c < 25; ++c) {
        const float* vc = vb + c * 300;
        float wa0 = wa[c * 3], wa1 = wa[c * 3 + 1], wa2 = wa[c * 3 + 2];
        acc0 += wa0 * vc[0] + wa1 * vc[60] + wa2 * vc[120];
        acc1 += wa0 * vc[1] + wa1 * vc[61] + wa2 * vc[121];
        acc2 += wa0 * vc[2] + wa1 * vc[62] + wa2 * vc[122];
      }
      int xb = o * 18 + h * 6 + j0;
      x2c[xb] = acc0; x2c[xb + 1] = acc1; x2c[xb + 2] = acc2;
    }
    __syncthreads();

    // S6b2: W[o,h,q2] += SC[q2, jc..jc+5] . x2c   (SC = [l02_w; r02_w])
#pragma unroll
    for (int kk = 0; kk < 30; ++kk) {
      int idx = tid + kk * 256;
      if (idx < 7500) {
        int o = idx / 60, r = idx % 60, hh = r / 20, q2 = r % 20;
        const float* scr = (q2 < 10) ? (P.l02_w + q2 * 30 + jc)
                                     : (P.r02_w + (q2 - 10) * 30 + jc);
        const float* xb = x2c + o * 18 + hh * 6;
        float s = wacc[kk];
        for (int j = 0; j < 6; ++j) s += scr[j] * xb[j];
        wacc[kk] = s;
      }
    }
    // no barrier needed: next S6a touches t only; bar after S6a protects x2c
  }

  // ---- S6.5: materialize W in LDS (region A is long dead) ----
#pragma unroll
  for (int kk = 0; kk < 30; ++kk) {
    int idx = tid + kk * 256;
    if (idx < 7500) W[idx] = wacc[kk];
  }
  __syncthreads();

  // ---- S7: zC = relu(conv_ca2(WL) + ca2_b*S02 + l02_b) ----
  for (int k = tid; k < 500; k += 256) {
    int c = k / 20, r = k % 20, h = r / 10, q = r % 10;
    float s = P.ca2_b[c] * cS02[q] + P.l02_b[q];
    const float* wb = P.ca2_w + c * 250;
    const float* Wb = W + h * 20 + q;
    for (int o = 0; o < 125; ++o) {
      s += wb[o * 2] * Wb[o * 60] + wb[o * 2 + 1] * Wb[o * 60 + 20];
    }
    zC[k] = fmaxf(s, 0.f);
  }
  __syncthreads();

  // ---- S8a: zCb = cb2(zC)+cb2_b ; yC2 = cc2(WR) + r02_b*sum(cc2_w) + cc2_b ----
  if (tid < 10) {
    int q = tid;
    float s = P.cb2_b[0];
    for (int c = 0; c < 25; ++c)
      for (int dh = 0; dh < 2; ++dh)
        s += P.cb2_w[c * 2 + dh] * zC[c * 20 + dh * 10 + q];
    zCb[q] = s;
  } else if (tid < 40) {
    int u = tid - 10, h = u / 10, q = u % 10;
    float s = P.r02_b[q] * cScc2[0] + P.cc2_b[0];
    for (int o = 0; o < 125; ++o) s += P.cc2_w[o] * W[o * 60 + h * 20 + 10 + q];
    yC2[h * 10 + q] = s;
  }
  __syncthreads();

  // ---- S8b: out[h] = fl_w . (zCb + yC2[h]) + fl_b ----
  if (tid < 3) {
    int h = tid;
    float s = P.fl_b[0];
    for (int q = 0; q < 10; ++q) s += P.fl_w[q] * (zCb[q] + yC2[h * 10 + q]);
    P.out[b * 3 + h] = s;
  }
}

extern "C" void kernel_launch(void* const* d_in, const int* in_sizes, int n_in,
                              void* d_out, int out_size, void* d_ws, size_t ws_size,
                              hipStream_t stream) {
  (void)n_in; (void)out_size; (void)d_ws; (void)ws_size;
  Params P;
  P.x     = (const float*)d_in[0];
  P.ca1_w = (const float*)d_in[1];  P.ca1_b = (const float*)d_in[2];
  P.l01_w = (const float*)d_in[3];  P.l01_b = (const float*)d_in[4];
  P.cb1_w = (const float*)d_in[5];  P.cb1_b = (const float*)d_in[6];
  P.cc1_w = (const float*)d_in[7];  P.cc1_b = (const float*)d_in[8];
  P.r01_w = (const float*)d_in[9];  P.r01_b = (const float*)d_in[10];
  P.c1_w  = (const float*)d_in[11]; P.c1_b  = (const float*)d_in[12];
  P.l1_w  = (const float*)d_in[13]; P.l1_b  = (const float*)d_in[14];
  P.c2_w  = (const float*)d_in[15]; P.c2_b  = (const float*)d_in[16];
  P.ca_w  = (const float*)d_in[17]; P.ca_b  = (const float*)d_in[18];
  P.ra_w  = (const float*)d_in[19]; P.ra_b  = (const float*)d_in[20];
  P.ca2_w = (const float*)d_in[21]; P.ca2_b = (const float*)d_in[22];
  P.l02_w = (const float*)d_in[23]; P.l02_b = (const float*)d_in[24];
  P.cb2_w = (const float*)d_in[25]; P.cb2_b = (const float*)d_in[26];
  P.cc2_w = (const float*)d_in[27]; P.cc2_b = (const float*)d_in[28];
  P.r02_w = (const float*)d_in[29]; P.r02_b = (const float*)d_in[30];
  P.fl_w  = (const float*)d_in[31]; P.fl_b  = (const float*)d_in[32];
  P.out   = (float*)d_out;

  int B = in_sizes[0] / 635;
  fused_renet<<<dim3(B), dim3(256), 0, stream>>>(P);
}

// Round 2
// 1754.116 us; speedup vs baseline: 1.0540x; 1.0540x over previous
//
#include <hip/hip_runtime.h>

// Fused tiny-net, one workgroup (256 thr) per sample.
// Round-2 restructure: j-chunked block B + block-C pushdown (no W/x2-full),
// register-tiled hot stages (4-wide o/m quads x 6-wide j), vectorized LDS.
// LDS = 10055 floats = 40.2KB -> 4 WG/CU (16 waves), VGPR class <=128.

struct Params {
  const float* x;
  const float* ca1_w; const float* ca1_b;
  const float* l01_w; const float* l01_b;
  const float* cb1_w; const float* cb1_b;
  const float* cc1_w; const float* cc1_b;
  const float* r01_w; const float* r01_b;
  const float* c1_w;  const float* c1_b;
  const float* l1_w;  const float* l1_b;
  const float* c2_w;  const float* c2_b;
  const float* ca_w;  const float* ca_b;
  const float* ra_w;  const float* ra_b;
  const float* ca2_w; const float* ca2_b;
  const float* l02_w; const float* l02_b;
  const float* cb2_w; const float* cb2_b;
  const float* cc2_w; const float* cc2_b;
  const float* r02_w; const float* r02_b;
  const float* fl_w;  const float* fl_b;
  float* out;
};

// LDS layout (float offsets):
//  zA   @0     [5][5][84] = 2100   (persists through all chunks)
//  yA   @2100  [5][84]    = 420    (persists; Q source)
//  C    @2520  xs[5][128]=640  | per-chunk: Ppc[5][7][16]=560 + Qc[5][16]=80
//  D    @3160  XLp[7][81]=567  | per-chunk: u[25][2][6]=300 + w1[3][6]=18
//  E    @3728  v[25][5][16]=2000 | epilogue: zC[500] + yC2[30] + zCb[10]
//  F    @5728  t[75][4][6] = 1800
//  G    @7528  x2c[125][3][6] = 2250
//  H    @9778  consts: S01[81] S1[30] SR[30] SAc[125] S02[10] Scc2[1]
#define LDS_FLOATS 10055

__global__ __launch_bounds__(256, 4)
void fused_renet(Params P) {
  __shared__ float lds[LDS_FLOATS];
  const int tid = threadIdx.x;
  const int b = blockIdx.x;

  float* zA   = lds + 0;
  float* yA   = lds + 2100;
  float* xs   = lds + 2520;
  float* Ppc  = lds + 2520;
  float* Qc   = lds + 3080;
  float* XLp  = lds + 3160;
  float* ubuf = lds + 3160;
  float* w1b  = lds + 3460;
  float* v    = lds + 3728;
  float* zC   = lds + 3728;
  float* yC2  = lds + 4240;
  float* zCb  = lds + 4272;
  float* tb   = lds + 5728;
  float* x2c  = lds + 7528;
  float* cS01 = lds + 9778;
  float* cS1  = lds + 9859;
  float* cSR  = lds + 9889;
  float* cSAc = lds + 9919;
  float* cS02 = lds + 10044;
  float* cScc2= lds + 10054;

  // ---- S0: load x, zero pads, derived constants ----
  const float* xg = P.x + b * 635;
  for (int k = tid; k < 635; k += 256) xs[(k / 127) * 128 + (k % 127)] = xg[k];
  for (int k = tid; k < 162; k += 256) XLp[(k / 81) * 486 + (k % 81)] = 0.f; // rows 0,6
  for (int k = tid; k < 277; k += 256) {
    float s = 0.f;
    if (k < 81)       { for (int i = 0; i < 127; ++i) s += P.l01_w[k * 127 + i]; cS01[k] = s; }
    else if (k < 111) { int j = k - 81;  for (int a = 0; a < 81; ++a) s += P.l1_w[j * 81 + a]; cS1[j] = s; }
    else if (k < 141) { int j = k - 111; for (int a = 0; a < 81; ++a) s += P.ra_w[j * 81 + a]; cSR[j] = s; }
    else if (k < 266) { int o = k - 141; for (int i = 0; i < 75; ++i) s += P.ca_w[o * 75 + i]; cSAc[o] = s; }
    else if (k < 276) { int q = k - 266; for (int j = 0; j < 30; ++j) s += P.l02_w[q * 30 + j]; cS02[q] = s; }
    else              { for (int o = 0; o < 125; ++o) s += P.cc2_w[o]; cScc2[0] = s; }
  }
  __syncthreads();

  // ---- S1: XL = l01*x (rows 1..5 of XLp), yA = r01*x + r01_b ----
  if (tid < 162) {
    const float* wr = (tid < 81) ? (P.l01_w + tid * 127) : (P.r01_w + (tid - 81) * 127);
    float a0 = 0, a1 = 0, a2 = 0, a3 = 0, a4 = 0;
    for (int i = 0; i < 124; i += 4) {
      float w0 = wr[i], w1_ = wr[i + 1], w2 = wr[i + 2], w3 = wr[i + 3];
      float4 x0 = *(const float4*)&xs[i];
      float4 x1 = *(const float4*)&xs[128 + i];
      float4 x2 = *(const float4*)&xs[256 + i];
      float4 x3 = *(const float4*)&xs[384 + i];
      float4 x4 = *(const float4*)&xs[512 + i];
      a0 += w0 * x0.x + w1_ * x0.y + w2 * x0.z + w3 * x0.w;
      a1 += w0 * x1.x + w1_ * x1.y + w2 * x1.z + w3 * x1.w;
      a2 += w0 * x2.x + w1_ * x2.y + w2 * x2.z + w3 * x2.w;
      a3 += w0 * x3.x + w1_ * x3.y + w2 * x3.z + w3 * x3.w;
      a4 += w0 * x4.x + w1_ * x4.y + w2 * x4.z + w3 * x4.w;
    }
    for (int i = 124; i < 127; ++i) {
      float w = wr[i];
      a0 += w * xs[i];       a1 += w * xs[128 + i]; a2 += w * xs[256 + i];
      a3 += w * xs[384 + i]; a4 += w * xs[512 + i];
    }
    if (tid < 81) {
      XLp[ 81 + tid] = a0; XLp[162 + tid] = a1; XLp[243 + tid] = a2;
      XLp[324 + tid] = a3; XLp[405 + tid] = a4;
    } else {
      int a = tid - 81; float rb = P.r01_b[a];
      yA[a] = a0 + rb; yA[84 + a] = a1 + rb; yA[168 + a] = a2 + rb;
      yA[252 + a] = a3 + rb; yA[336 + a] = a4 + rb;
    }
  }
  __syncthreads();

  // ---- S2: zA = relu(conv_ca1(XL) + ca1_b*S01 + l01_b); zero Ppc pad rows ----
  for (int k = tid; k < 2025; k += 256) {
    int c5 = k / 405, r = k % 405, h = r / 81, a = r % 81;
    float s = P.ca1_b[c5] * cS01[a] + P.l01_b[a];
    for (int dh = 0; dh < 3; ++dh) s += P.ca1_w[c5 * 3 + dh] * XLp[(h + dh) * 81 + a];
    zA[c5 * 420 + h * 84 + a] = fmaxf(s, 0.f);
  }
  for (int k = tid; k < 160; k += 256) {
    int c5 = k / 32, r = k % 32;
    Ppc[c5 * 112 + (r / 16) * 96 + (r % 16)] = 0.f;   // rows 0 and 6 of each c5 slab
  }

  float zacc0 = 0.f, zacc1 = 0.f, yaccr = 0.f;

  auto do_acc = [&](int jp) {
    {
      int e = tid; // always < 500
      int c = e / 20, hq = e % 20, hh = hq / 10, q = hq % 10;
      const float* lr = P.l02_w + q * 30 + jp;
      const float* ub = ubuf + (c * 2 + hh) * 6;
#pragma unroll
      for (int jl = 0; jl < 6; ++jl) zacc0 += lr[jl] * ub[jl];
    }
    if (tid < 244) {
      int e = tid + 256;
      int c = e / 20, hq = e % 20, hh = hq / 10, q = hq % 10;
      const float* lr = P.l02_w + q * 30 + jp;
      const float* ub = ubuf + (c * 2 + hh) * 6;
#pragma unroll
      for (int jl = 0; jl < 6; ++jl) zacc1 += lr[jl] * ub[jl];
    }
    if (tid < 30) {
      int hh = tid / 10, q = tid % 10;
      const float* rr = P.r02_w + q * 30 + jp;
      const float* wb = w1b + hh * 6;
#pragma unroll
      for (int jl = 0; jl < 6; ++jl) yaccr += rr[jl] * wb[jl];
    }
  };

  for (int ci = 0; ci < 5; ++ci) {
    const int jc = ci * 6;
    __syncthreads();

    // ---- PQ (+ ACC of previous chunk) ----
    if (ci > 0) do_acc(jc - 6);
    if (tid < 150) {
      int c5 = tid / 30, r = tid % 30, h = r / 6, r2 = r % 6, half = r2 / 3, jp2 = r2 % 3;
      int j0 = jc + 2 * jp2;
      const float* sw0 = half ? (P.ra_w + j0 * 81) : (P.l1_w + j0 * 81);
      const float* sw1 = sw0 + 81;
      const float* zr = zA + c5 * 420 + h * 84;
      float s0 = 0.f, s1 = 0.f;
      for (int a = 0; a < 80; a += 4) {
        float4 z4 = *(const float4*)&zr[a];
        s0 += sw0[a] * z4.x + sw0[a + 1] * z4.y + sw0[a + 2] * z4.z + sw0[a + 3] * z4.w;
        s1 += sw1[a] * z4.x + sw1[a + 1] * z4.y + sw1[a + 2] * z4.z + sw1[a + 3] * z4.w;
      }
      s0 += sw0[80] * zr[80]; s1 += sw1[80] * zr[80];
      float* pp = Ppc + c5 * 112 + (h + 1) * 16 + half * 8 + 2 * jp2;
      pp[0] = s0; pp[1] = s1;
    } else if (tid < 210) {
      int u2 = tid - 150, h = u2 / 12, r2 = u2 % 12, half = r2 / 6, jl = r2 % 6;
      int j2 = jc + jl;
      const float* sw = half ? (P.ra_w + j2 * 81) : (P.l1_w + j2 * 81);
      const float* yr = yA + h * 84;
      float s = 0.f;
      for (int a = 0; a < 81; ++a) s += sw[a] * yr[a];
      Qc[h * 16 + half * 8 + jl] = s;
    }
    __syncthreads();

    // ---- V: v-chunk [25][5][16] (VL @0..5, VR @8..13) ----
    if (tid < 250) {
      int c = tid / 10, r = tid % 10, h = r / 2, g = r % 2;
      float bb = P.cb1_b[c] + P.cc1_b[c];
      float cw = P.cc1_w[c];
      const float* q4 = Qc + h * 16 + g * 8;
      float s[6];
#pragma unroll
      for (int jl = 0; jl < 6; ++jl) {
        float srow = g ? cSR[jc + jl] : cS1[jc + jl];
        s[jl] = cw * q4[jl] + bb * srow;
      }
#pragma unroll
      for (int c5 = 0; c5 < 5; ++c5) {
        const float* wb = P.cb1_w + c * 15 + c5 * 3;
        const float* pr = Ppc + c5 * 112 + h * 16 + g * 8;
#pragma unroll
        for (int dh = 0; dh < 3; ++dh) {
          float w = wb[dh];
          const float* p = pr + dh * 16;
          float4 p4 = *(const float4*)p;
          float2 p2 = *(const float2*)(p + 4);
          s[0] += w * p4.x; s[1] += w * p4.y; s[2] += w * p4.z;
          s[3] += w * p4.w; s[4] += w * p2.x; s[5] += w * p2.y;
        }
      }
      float* vp = v + c * 80 + h * 16 + g * 8;
      *(float4*)vp = make_float4(s[0], s[1], s[2], s[3]);
      *(float2*)(vp + 4) = make_float2(s[4], s[5]);
    }
    __syncthreads();

    // ---- T: t-chunk [75][4][6], unit=(m-quad,h), 4x6 acc tile ----
    if (tid < 76) {
      int mq = tid >> 2, h = tid & 3;
      int mb = 4 * mq; if (mb > 71) mb = 71;
      float acc[4][6];
#pragma unroll
      for (int jl = 0; jl < 6; ++jl) {
        float lb = P.l1_b[jc + jl], s1v = cS1[jc + jl];
#pragma unroll
        for (int i = 0; i < 4; ++i) acc[i][jl] = P.c1_b[mb + i] * s1v + lb;
      }
      for (int c = 0; c < 25; ++c) {
        const float* vr = v + c * 80 + h * 16;
        float4 a4 = *(const float4*)vr;        float2 a2 = *(const float2*)(vr + 4);
        float4 b4 = *(const float4*)(vr + 16); float2 b2 = *(const float2*)(vr + 20);
#pragma unroll
        for (int i = 0; i < 4; ++i) {
          float2 w = *(const float2*)(P.c1_w + (mb + i) * 50 + c * 2);
          acc[i][0] += w.x * a4.x + w.y * b4.x;
          acc[i][1] += w.x * a4.y + w.y * b4.y;
          acc[i][2] += w.x * a4.z + w.y * b4.z;
          acc[i][3] += w.x * a4.w + w.y * b4.w;
          acc[i][4] += w.x * a2.x + w.y * b2.x;
          acc[i][5] += w.x * a2.y + w.y * b2.y;
        }
      }
#pragma unroll
      for (int i = 0; i < 4; ++i) {
        float* tp = tb + (mb + i) * 24 + h * 6;
        *(float2*)(tp)     = make_float2(fmaxf(acc[i][0], 0.f), fmaxf(acc[i][1], 0.f));
        *(float2*)(tp + 2) = make_float2(fmaxf(acc[i][2], 0.f), fmaxf(acc[i][3], 0.f));
        *(float2*)(tp + 4) = make_float2(fmaxf(acc[i][4], 0.f), fmaxf(acc[i][5], 0.f));
      }
    }
    __syncthreads();

    // ---- X2: x2-chunk [125][3][6], unit=(o-quad,h), 4x6 acc tile ----
    if (tid < 96) {
      int og = tid / 3, h = tid % 3;
      int ob = 4 * og; if (ob > 121) ob = 121;
      float rb6[6];
#pragma unroll
      for (int jl = 0; jl < 6; ++jl) rb6[jl] = P.ra_b[jc + jl];
      float x[4][6];
#pragma unroll
      for (int i = 0; i < 4; ++i) {
        int o = ob + i;
        float base = P.c2_b[o] + P.ca_b[o];
        float sac = cSAc[o];
#pragma unroll
        for (int jl = 0; jl < 6; ++jl) x[i][jl] = base + rb6[jl] * sac;
      }
      for (int m = 0; m < 75; ++m) {
        const float* t0 = tb + m * 24 + h * 6;
        float2 r0a = *(const float2*)t0,       r0b = *(const float2*)(t0 + 2), r0c = *(const float2*)(t0 + 4);
        float2 r1a = *(const float2*)(t0 + 6), r1b = *(const float2*)(t0 + 8), r1c = *(const float2*)(t0 + 10);
#pragma unroll
        for (int i = 0; i < 4; ++i) {
          float2 w = *(const float2*)(P.c2_w + (ob + i) * 150 + 2 * m);
          x[i][0] += w.x * r0a.x + w.y * r1a.x;
          x[i][1] += w.x * r0a.y + w.y * r1a.y;
          x[i][2] += w.x * r0b.x + w.y * r1b.x;
          x[i][3] += w.x * r0b.y + w.y * r1b.y;
          x[i][4] += w.x * r0c.x + w.y * r1c.x;
          x[i][5] += w.x * r0c.y + w.y * r1c.y;
        }
      }
      for (int c = 0; c < 25; ++c) {
        const float* vr = v + c * 80 + h * 16 + 8;
        float4 pa = *(const float4*)vr;        float2 pb = *(const float2*)(vr + 4);
        float4 qa = *(const float4*)(vr + 16); float2 qb = *(const float2*)(vr + 20);
        float4 ra = *(const float4*)(vr + 32); float2 rc = *(const float2*)(vr + 36);
#pragma unroll
        for (int i = 0; i < 4; ++i) {
          const float* wp = P.ca_w + (ob + i) * 75 + 3 * c;
          float wa0 = wp[0], wa1 = wp[1], wa2 = wp[2];
          x[i][0] += wa0 * pa.x + wa1 * qa.x + wa2 * ra.x;
          x[i][1] += wa0 * pa.y + wa1 * qa.y + wa2 * ra.y;
          x[i][2] += wa0 * pa.z + wa1 * qa.z + wa2 * ra.z;
          x[i][3] += wa0 * pa.w + wa1 * qa.w + wa2 * ra.w;
          x[i][4] += wa0 * pb.x + wa1 * qb.x + wa2 * rc.x;
          x[i][5] += wa0 * pb.y + wa1 * qb.y + wa2 * rc.y;
        }
      }
#pragma unroll
      for (int i = 0; i < 4; ++i) {
        float* xp = x2c + (ob + i) * 18 + h * 6;
        *(float2*)(xp)     = make_float2(x[i][0], x[i][1]);
        *(float2*)(xp + 2) = make_float2(x[i][2], x[i][3]);
        *(float2*)(xp + 4) = make_float2(x[i][4], x[i][5]);
      }
    }
    __syncthreads();

    // ---- U: u[25][2][6] = contract o,dh over x2; w1[3][6] = cc2 . x2 ----
    if (tid < 42) {
      int cq = tid / 6, r = tid % 6, hh = r / 3, g = r % 3;
      int cb = 4 * cq; if (cb > 21) cb = 21;
      float acc[4][2] = {{0.f,0.f},{0.f,0.f},{0.f,0.f},{0.f,0.f}};
      for (int o = 0; o < 125; ++o) {
#pragma unroll
        for (int dh = 0; dh < 2; ++dh) {
          float2 xp = *(const float2*)(x2c + o * 18 + (hh + dh) * 6 + 2 * g);
#pragma unroll
          for (int i = 0; i < 4; ++i) {
            float w = P.ca2_w[(cb + i) * 250 + o * 2 + dh];
            acc[i][0] += w * xp.x; acc[i][1] += w * xp.y;
          }
        }
      }
#pragma unroll
      for (int i = 0; i < 4; ++i) {
        float* up = ubuf + ((cb + i) * 2 + hh) * 6 + 2 * g;
        up[0] = acc[i][0]; up[1] = acc[i][1];
      }
    } else if (tid < 51) {
      int r = tid - 42, hh = r / 3, g = r % 3;
      float a0 = 0.f, a1 = 0.f;
      for (int o = 0; o < 125; ++o) {
        float w = P.cc2_w[o];
        float2 xp = *(const float2*)(x2c + o * 18 + hh * 6 + 2 * g);
        a0 += w * xp.x; a1 += w * xp.y;
      }
      w1b[hh * 6 + 2 * g] = a0; w1b[hh * 6 + 2 * g + 1] = a1;
    }
    __syncthreads();
  }

  // ---- epilogue: final ACC, block C tail ----
  do_acc(24);
  {
    int e = tid; // < 500 always
    int c = e / 20, hq = e % 20, hh = hq / 10, q = hq % 10;
    zC[e] = fmaxf(zacc0 + P.ca2_b[c] * cS02[q] + P.l02_b[q], 0.f);
  }
  if (tid < 244) {
    int e = tid + 256;
    int c = e / 20, hq = e % 20, hh = hq / 10, q = hq % 10;
    (void)hh;
    zC[e] = fmaxf(zacc1 + P.ca2_b[c] * cS02[q] + P.l02_b[q], 0.f);
  }
  if (tid < 30) yC2[tid] = yaccr + P.r02_b[tid % 10] * cScc2[0] + P.cc2_b[0];
  __syncthreads();

  if (tid < 10) {
    float s = P.cb2_b[0];
    for (int c = 0; c < 25; ++c)
#pragma unroll
      for (int dh = 0; dh < 2; ++dh)
        s += P.cb2_w[c * 2 + dh] * zC[c * 20 + dh * 10 + tid];
    zCb[tid] = s;
  }
  __syncthreads();

  if (tid < 3) {
    float s = P.fl_b[0];
    for (int q = 0; q < 10; ++q) s += P.fl_w[q] * (zCb[q] + yC2[tid * 10 + q]);
    P.out[b * 3 + tid] = s;
  }
}

extern "C" void kernel_launch(void* const* d_in, const int* in_sizes, int n_in,
                              void* d_out, int out_size, void* d_ws, size_t ws_size,
                              hipStream_t stream) {
  (void)n_in; (void)out_size; (void)d_ws; (void)ws_size;
  Params P;
  P.x     = (const float*)d_in[0];
  P.ca1_w = (const float*)d_in[1];  P.ca1_b = (const float*)d_in[2];
  P.l01_w = (const float*)d_in[3];  P.l01_b = (const float*)d_in[4];
  P.cb1_w = (const float*)d_in[5];  P.cb1_b = (const float*)d_in[6];
  P.cc1_w = (const float*)d_in[7];  P.cc1_b = (const float*)d_in[8];
  P.r01_w = (const float*)d_in[9];  P.r01_b = (const float*)d_in[10];
  P.c1_w  = (const float*)d_in[11]; P.c1_b  = (const float*)d_in[12];
  P.l1_w  = (const float*)d_in[13]; P.l1_b  = (const float*)d_in[14];
  P.c2_w  = (const float*)d_in[15]; P.c2_b  = (const float*)d_in[16];
  P.ca_w  = (const float*)d_in[17]; P.ca_b  = (const float*)d_in[18];
  P.ra_w  = (const float*)d_in[19]; P.ra_b  = (const float*)d_in[20];
  P.ca2_w = (const float*)d_in[21]; P.ca2_b = (const float*)d_in[22];
  P.l02_w = (const float*)d_in[23]; P.l02_b = (const float*)d_in[24];
  P.cb2_w = (const float*)d_in[25]; P.cb2_b = (const float*)d_in[26];
  P.cc2_w = (const float*)d_in[27]; P.cc2_b = (const float*)d_in[28];
  P.r02_w = (const float*)d_in[29]; P.r02_b = (const float*)d_in[30];
  P.fl_w  = (const float*)d_in[31]; P.fl_b  = (const float*)d_in[32];
  P.out   = (float*)d_out;

  int B = in_sizes[0] / 635;
  fused_renet<<<dim3(B), dim3(256), 0, stream>>>(P);
}

// Round 3
// 1225.731 us; speedup vs baseline: 1.5084x; 1.4311x over previous
//
#include <hip/hip_runtime.h>

// Round 3: batch-major multi-kernel pipeline.
// Activations: global bf16 [feature_row][CB] (batch fast, lane=sample, coalesced).
// Weights: pre-transposed fp32 in d_ws so per-K-step weight vectors are
// contiguous -> wave-uniform s_load; FMAs are v_fmac with SGPR operand.
// No LDS in hot loops. 11 kernels per chunk; buffer lifetimes overlapped.

typedef unsigned short u16;

__device__ __forceinline__ float bf2f(u16 u) {
  return __uint_as_float(((unsigned)u) << 16);
}
__device__ __forceinline__ u16 f2bf(float f) {
  unsigned u = __float_as_uint(f);
  return (u16)((u + 0x7FFFu + ((u >> 16) & 1u)) >> 16);   // RNE
}

// ---- fp32 ws region offsets (floats) ----
#define OF_CS01   0        // 81
#define OF_CS1    81       // 30
#define OF_CSR    111      // 30
#define OF_CSAC   141      // 125
#define OF_CS02   266      // 10
#define OF_CSCC2  276      // 1
#define OF_L01T   277      // 127*81
#define OF_R01T   10564    // 127*81
#define OF_SWT    20851    // 81*60
#define OF_CB1T   25711    // 15*25
#define OF_C1T    26086    // 50*75
#define OF_C2T    29836    // 150*128 (o padded to 128)
#define OF_CAT    49036    // 75*128  (o padded to 128)
#define OF_SCT    58636    // 30*20
#define OF_CA2T   59236    // 250*25
#define F32_TOTAL 65486

// ---- activation pool row offsets (pitch = CB, bf16), lifetimes overlapped ----
#define R_XT   0      // 635   [K0T..K1]
#define R_XL   635    // 405   [K1..K2]
#define R_YA   1040   // 405   [K1..K3]
#define R_ZA   1445   // 2025  [K2..K3]
#define R_P    3470   // 1500  [K3..K4]
#define R_Q    4970   // 300   [K3..K4]
#define R_V    11250  // 7500  [K4..K6]
#define R_T    18750  // 9000  [K5..K6]
#define R_X2   0      // 11250 [K6..K7]  (reuses early region)
#define R_XJ   11250  // 7500  [K7..K8b] (reuses v)
#define R_ZC   18750  // 500   [K8a..K8b](reuses t)
#define ROWS_TOTAL 27750

struct Ctx {
  // raw inputs
  const float *x, *ca1_w, *ca1_b, *l01_b, *r01_b, *cb1_b, *cc1_w, *cc1_b;
  const float *c1_b, *l1_b, *c2_b, *ca_b, *ra_b, *ca2_b, *l02_b;
  const float *cb2_w, *cb2_b, *cc2_w, *cc2_b, *r02_b, *fl_w, *fl_b;
  const float *l01_w, *r01_w, *l1_w, *ra_w, *c1_w, *c2_w, *ca_w, *cb1_w;
  const float *l02_w, *r02_w, *ca2_w;
  // derived fp32 (in ws)
  float *F;         // base of fp32 region
  // activation pool
  u16 *A;           // base of bf16 pool
  float *out;
  int CB;           // chunk batch size (cols)
  int b0g;          // global batch offset of this chunk
};

// ---------- K0C: constants + transposed weights (one block) ----------
__global__ __launch_bounds__(256) void k0c(Ctx C) {
  const int tid = threadIdx.x;
  float* F = C.F;
  for (int k = tid; k < 277; k += 256) {
    float s = 0.f;
    if (k < 81)       { for (int i = 0; i < 127; ++i) s += C.l01_w[k * 127 + i]; F[OF_CS01 + k] = s; }
    else if (k < 111) { int j = k - 81;  for (int a = 0; a < 81; ++a) s += C.l1_w[j * 81 + a]; F[OF_CS1 + j] = s; }
    else if (k < 141) { int j = k - 111; for (int a = 0; a < 81; ++a) s += C.ra_w[j * 81 + a]; F[OF_CSR + j] = s; }
    else if (k < 266) { int o = k - 141; for (int i = 0; i < 75; ++i) s += C.ca_w[o * 75 + i]; F[OF_CSAC + o] = s; }
    else if (k < 276) { int q = k - 266; for (int j = 0; j < 30; ++j) s += C.l02_w[q * 30 + j]; F[OF_CS02 + q] = s; }
    else              { for (int o = 0; o < 125; ++o) s += C.cc2_w[o]; F[OF_CSCC2] = s; }
  }
  for (int e = tid; e < 10287; e += 256) { int i = e / 81, a = e % 81; F[OF_L01T + e] = C.l01_w[a * 127 + i]; }
  for (int e = tid; e < 10287; e += 256) { int i = e / 81, a = e % 81; F[OF_R01T + e] = C.r01_w[a * 127 + i]; }
  for (int e = tid; e < 4860; e += 256)  { int a = e / 60, j2 = e % 60;
    F[OF_SWT + e] = (j2 < 30) ? C.l1_w[j2 * 81 + a] : C.ra_w[(j2 - 30) * 81 + a]; }
  for (int e = tid; e < 375; e += 256)   { int k = e / 25, c = e % 25; F[OF_CB1T + e] = C.cb1_w[c * 15 + k]; }
  for (int e = tid; e < 3750; e += 256)  { int k = e / 75, m = e % 75; F[OF_C1T + e] = C.c1_w[m * 50 + k]; }
  for (int e = tid; e < 19200; e += 256) { int k = e / 128, o = e % 128;
    F[OF_C2T + e] = (o < 125) ? C.c2_w[o * 150 + k] : 0.f; }
  for (int e = tid; e < 9600; e += 256)  { int k = e / 128, o = e % 128;
    F[OF_CAT + e] = (o < 125) ? C.ca_w[o * 75 + k] : 0.f; }
  for (int e = tid; e < 600; e += 256)   { int j = e / 20, q2 = e % 20;
    F[OF_SCT + e] = (q2 < 10) ? C.l02_w[q2 * 30 + j] : C.r02_w[(q2 - 10) * 30 + j]; }
  for (int e = tid; e < 6250; e += 256)  { int k = e / 25, c = e % 25; F[OF_CA2T + e] = C.ca2_w[c * 250 + k]; }
}

// ---------- K0T: transpose x -> xT[635][CB] bf16. grid (CB/64, 10) ----------
__global__ __launch_bounds__(256) void k0t(Ctx C) {
  __shared__ float tile[64][65];
  const int tid = threadIdx.x;
  const int b0 = blockIdx.x * 64;
  const int i0 = blockIdx.y * 64;
  for (int e = tid; e < 64 * 64; e += 256) {
    int s = e >> 6, ii = e & 63, gi = i0 + ii;
    if (gi < 635) tile[s][ii] = C.x[(size_t)(C.b0g + b0 + s) * 635 + gi];
  }
  __syncthreads();
  const int lane = tid & 63, wv = tid >> 6;
  u16* xT = C.A + (size_t)R_XT * C.CB;
#pragma unroll
  for (int k = 0; k < 16; ++k) {
    int r = wv * 16 + k, gi = i0 + r;
    if (gi < 635) xT[(size_t)gi * C.CB + b0 + lane] = f2bf(tile[lane][r]);
  }
}

// ---------- K1: XL = l01*x, yA = r01*x + r01_b. grid (CB/256, 10) ----------
__global__ __launch_bounds__(256) void k1(Ctx C) {
  const int col = blockIdx.x * 256 + threadIdx.x;
  if (col >= C.CB) return;
  const int g = blockIdx.y, type = g / 5, h = g % 5;
  const u16* __restrict__ xT = C.A + (size_t)R_XT * C.CB;
  const float* __restrict__ wT = C.F + (type ? OF_R01T : OF_L01T);
  float acc[81];
#pragma unroll
  for (int a = 0; a < 81; ++a) acc[a] = 0.f;
  for (int i = 0; i < 127; ++i) {
    float xv = bf2f(xT[(size_t)(h * 127 + i) * C.CB + col]);
    const float* __restrict__ w = wT + i * 81;
#pragma unroll
    for (int a = 0; a < 81; ++a) acc[a] += w[a] * xv;
  }
  u16* dst = C.A + (size_t)(type ? R_YA : R_XL) * C.CB;
#pragma unroll
  for (int a = 0; a < 81; ++a) {
    float r = acc[a] + (type ? C.r01_b[a] : 0.f);
    dst[(size_t)(h * 81 + a) * C.CB + col] = f2bf(r);
  }
}

// ---------- K2: zA = relu(conv_ca1(XL) + ca1_b*S01 + l01_b). grid (CB/256, 25) ----------
__global__ __launch_bounds__(256) void k2(Ctx C) {
  const int col = blockIdx.x * 256 + threadIdx.x;
  if (col >= C.CB) return;
  const int g = blockIdx.y, c5 = g / 5, h = g % 5;
  const u16* __restrict__ XL = C.A + (size_t)R_XL * C.CB;
  const float* __restrict__ F = C.F;
  float acc[81];
  float cb = C.ca1_b[c5];
#pragma unroll
  for (int a = 0; a < 81; ++a) acc[a] = cb * F[OF_CS01 + a] + C.l01_b[a];
  for (int dh = 0; dh < 3; ++dh) {
    int hp = h - 1 + dh;
    if (hp < 0 || hp > 4) continue;
    float w = C.ca1_w[c5 * 3 + dh];
#pragma unroll
    for (int a = 0; a < 81; ++a) acc[a] += w * bf2f(XL[(size_t)(hp * 81 + a) * C.CB + col]);
  }
  u16* zA = C.A + (size_t)R_ZA * C.CB;
#pragma unroll
  for (int a = 0; a < 81; ++a)
    zA[(size_t)(g * 81 + a) * C.CB + col] = f2bf(fmaxf(acc[a], 0.f));
}

// ---------- K3: P = SW*zA, Q = SW*yA. grid (CB/256, 30) ----------
__global__ __launch_bounds__(256) void k3(Ctx C) {
  const int col = blockIdx.x * 256 + threadIdx.x;
  if (col >= C.CB) return;
  const int g = blockIdx.y;
  const bool isP = (g < 25);
  const u16* __restrict__ src = C.A + (size_t)(isP ? (R_ZA + g * 81) : (R_YA + (g - 25) * 81)) * C.CB;
  const float* __restrict__ SWT = C.F + OF_SWT;
  float acc[60];
#pragma unroll
  for (int j = 0; j < 60; ++j) acc[j] = 0.f;
  for (int a = 0; a < 81; ++a) {
    float xv = bf2f(src[(size_t)a * C.CB + col]);
    const float* __restrict__ w = SWT + a * 60;
#pragma unroll
    for (int j = 0; j < 60; ++j) acc[j] += w[j] * xv;
  }
  u16* dst = C.A + (size_t)(isP ? (R_P + g * 60) : (R_Q + (g - 25) * 60)) * C.CB;
#pragma unroll
  for (int j = 0; j < 60; ++j) dst[(size_t)j * C.CB + col] = f2bf(acc[j]);
}

// ---------- K4: v = conv_cb1(P) + cc1_w*Q + bias. grid (CB/256, 300) ----------
__global__ __launch_bounds__(256) void k4(Ctx C) {
  const int col = blockIdx.x * 256 + threadIdx.x;
  if (col >= C.CB) return;
  const int g = blockIdx.y, h = g / 60, j2 = g % 60;
  const u16* __restrict__ Pb = C.A + (size_t)R_P * C.CB;
  const u16* __restrict__ Qb = C.A + (size_t)R_Q * C.CB;
  const float* __restrict__ F = C.F;
  float qv = bf2f(Qb[(size_t)(h * 60 + j2) * C.CB + col]);
  float sj = (j2 < 30) ? F[OF_CS1 + j2] : F[OF_CSR + (j2 - 30)];
  float acc[25];
#pragma unroll
  for (int c = 0; c < 25; ++c) acc[c] = C.cc1_w[c] * qv + (C.cb1_b[c] + C.cc1_b[c]) * sj;
  for (int k = 0; k < 15; ++k) {
    int c5 = k / 3, dh = k % 3, hp = h - 1 + dh;
    if (hp < 0 || hp > 4) continue;
    float xv = bf2f(Pb[(size_t)((c5 * 5 + hp) * 60 + j2) * C.CB + col]);
    const float* __restrict__ w = F + OF_CB1T + k * 25;
#pragma unroll
    for (int c = 0; c < 25; ++c) acc[c] += w[c] * xv;
  }
  u16* vb = C.A + (size_t)R_V * C.CB;
#pragma unroll
  for (int c = 0; c < 25; ++c)
    vb[(size_t)((c * 5 + h) * 60 + j2) * C.CB + col] = f2bf(acc[c]);
}

// ---------- K5: t = relu(conv_c1(vL) + c1_b*S1 + l1_b). grid (CB/256, 120) ----------
__global__ __launch_bounds__(256) void k5(Ctx C) {
  const int col = blockIdx.x * 256 + threadIdx.x;
  if (col >= C.CB) return;
  const int g = blockIdx.y, h4 = g / 30, j = g % 30;
  const u16* __restrict__ vb = C.A + (size_t)R_V * C.CB;
  const float* __restrict__ F = C.F;
  float acc[75];
#pragma unroll
  for (int m = 0; m < 75; ++m) acc[m] = 0.f;
  for (int k = 0; k < 50; ++k) {
    int c = k >> 1, dc = k & 1;
    float xv = bf2f(vb[(size_t)((c * 5 + h4 + dc) * 60 + j) * C.CB + col]);
    const float* __restrict__ w = F + OF_C1T + k * 75;
#pragma unroll
    for (int m = 0; m < 75; ++m) acc[m] += w[m] * xv;
  }
  u16* tb = C.A + (size_t)R_T * C.CB;
  float s1 = F[OF_CS1 + j];
#pragma unroll
  for (int m = 0; m < 75; ++m) {
    float r = acc[m] + C.c1_b[m] * s1 + C.l1_b[j];
    tb[(size_t)((m * 4 + h4) * 30 + j) * C.CB + col] = f2bf(fmaxf(r, 0.f));
  }
}

// ---------- K6: x2 = conv_c2(t) + conv_ca(vR) + bias. grid (CB/64, 90), 4 o-passes ----------
__global__ __launch_bounds__(256) void k6(Ctx C) {
  const int tid = threadIdx.x;
  const int col = blockIdx.x * 64 + (tid & 63);
  const int ow = __builtin_amdgcn_readfirstlane(tid >> 6) * 32;
  const int g = blockIdx.y, h3 = g / 30, j = g % 30;
  const u16* __restrict__ tb = C.A + (size_t)R_T * C.CB;
  const u16* __restrict__ vb = C.A + (size_t)R_V * C.CB;
  const float* __restrict__ F = C.F;
  float acc[32];
#pragma unroll
  for (int i = 0; i < 32; ++i) acc[i] = 0.f;
  for (int k = 0; k < 150; ++k) {
    int m = k >> 1, dc = k & 1;
    float xv = bf2f(tb[(size_t)((m * 4 + h3 + dc) * 30 + j) * C.CB + col]);
    const float* __restrict__ w = F + OF_C2T + k * 128 + ow;
#pragma unroll
    for (int i = 0; i < 32; ++i) acc[i] += w[i] * xv;
  }
  for (int k = 0; k < 75; ++k) {
    int c = k / 3, dc3 = k % 3;
    float xv = bf2f(vb[(size_t)((c * 5 + h3 + dc3) * 60 + 30 + j) * C.CB + col]);
    const float* __restrict__ w = F + OF_CAT + k * 128 + ow;
#pragma unroll
    for (int i = 0; i < 32; ++i) acc[i] += w[i] * xv;
  }
  u16* x2b = C.A + (size_t)R_X2 * C.CB;
  float rbj = C.ra_b[j];
#pragma unroll
  for (int i = 0; i < 32; ++i) {
    int o = ow + i;
    if (o < 125) {
      float r = acc[i] + C.c2_b[o] + C.ca_b[o] + rbj * F[OF_CSAC + o];
      x2b[(size_t)((o * 3 + h3) * 30 + j) * C.CB + col] = f2bf(r);
    }
  }
}

// ---------- K7: XJ = SC * x2 (contract j). grid (CB/256, 375) ----------
__global__ __launch_bounds__(256) void k7(Ctx C) {
  const int col = blockIdx.x * 256 + threadIdx.x;
  if (col >= C.CB) return;
  const int g = blockIdx.y;               // g = o*3 + h3
  const u16* __restrict__ x2b = C.A + (size_t)R_X2 * C.CB;
  const float* __restrict__ SCT = C.F + OF_SCT;
  float acc[20];
#pragma unroll
  for (int q = 0; q < 20; ++q) acc[q] = 0.f;
  for (int j = 0; j < 30; ++j) {
    float xv = bf2f(x2b[(size_t)(g * 30 + j) * C.CB + col]);
    const float* __restrict__ w = SCT + j * 20;
#pragma unroll
    for (int q = 0; q < 20; ++q) acc[q] += w[q] * xv;
  }
  u16* XJ = C.A + (size_t)R_XJ * C.CB;
#pragma unroll
  for (int q = 0; q < 20; ++q) XJ[(size_t)(g * 20 + q) * C.CB + col] = f2bf(acc[q]);
}

// ---------- K8a: zC = relu(conv_ca2(XJ_l) + ca2_b*S02 + l02_b). grid (CB/256, 20) ----------
__global__ __launch_bounds__(256) void k8a(Ctx C) {
  const int col = blockIdx.x * 256 + threadIdx.x;
  if (col >= C.CB) return;
  const int g = blockIdx.y, hh = g / 10, q = g % 10;
  const u16* __restrict__ XJ = C.A + (size_t)R_XJ * C.CB;
  const float* __restrict__ F = C.F;
  float acc[25];
#pragma unroll
  for (int c = 0; c < 25; ++c) acc[c] = 0.f;
  for (int k = 0; k < 250; ++k) {
    int o = k >> 1, dh = k & 1;
    float xv = bf2f(XJ[(size_t)((o * 3 + hh + dh) * 20 + q) * C.CB + col]);
    const float* __restrict__ w = F + OF_CA2T + k * 25;
#pragma unroll
    for (int c = 0; c < 25; ++c) acc[c] += w[c] * xv;
  }
  u16* zC = C.A + (size_t)R_ZC * C.CB;
  float s02 = F[OF_CS02 + q];
#pragma unroll
  for (int c = 0; c < 25; ++c) {
    float r = acc[c] + C.ca2_b[c] * s02 + C.l02_b[q];
    zC[(size_t)((c * 2 + hh) * 10 + q) * C.CB + col] = f2bf(fmaxf(r, 0.f));
  }
}

// ---------- K8b: tail -> out. grid (CB/256, 1) ----------
__global__ __launch_bounds__(256) void k8b(Ctx C) {
  const int col = blockIdx.x * 256 + threadIdx.x;
  if (col >= C.CB) return;
  const u16* __restrict__ zC = C.A + (size_t)R_ZC * C.CB;
  const u16* __restrict__ XJ = C.A + (size_t)R_XJ * C.CB;
  const float* __restrict__ F = C.F;
  float zf[10];
#pragma unroll
  for (int q = 0; q < 10; ++q) zf[q] = C.cb2_b[0];
  for (int k = 0; k < 50; ++k) {
    float w = C.cb2_w[k];
#pragma unroll
    for (int q = 0; q < 10; ++q) zf[q] += w * bf2f(zC[(size_t)(k * 10 + q) * C.CB + col]);
  }
  float yc[3][10];
#pragma unroll
  for (int h = 0; h < 3; ++h)
#pragma unroll
    for (int q = 0; q < 10; ++q) yc[h][q] = 0.f;
  for (int o = 0; o < 125; ++o) {
    float w = C.cc2_w[o];
#pragma unroll
    for (int h = 0; h < 3; ++h)
#pragma unroll
      for (int q = 0; q < 10; ++q)
        yc[h][q] += w * bf2f(XJ[(size_t)((o * 3 + h) * 20 + 10 + q) * C.CB + col]);
  }
  float sc = F[OF_CSCC2];
#pragma unroll
  for (int h = 0; h < 3; ++h) {
    float s = C.fl_b[0];
#pragma unroll
    for (int q = 0; q < 10; ++q)
      s += C.fl_w[q] * (zf[q] + yc[h][q] + C.r02_b[q] * sc + C.cc2_b[0]);
    C.out[(size_t)(C.b0g + col) * 3 + h] = s;
  }
}

extern "C" void kernel_launch(void* const* d_in, const int* in_sizes, int n_in,
                              void* d_out, int out_size, void* d_ws, size_t ws_size,
                              hipStream_t stream) {
  (void)n_in; (void)out_size;
  Ctx C;
  C.x     = (const float*)d_in[0];
  C.ca1_w = (const float*)d_in[1];  C.ca1_b = (const float*)d_in[2];
  C.l01_w = (const float*)d_in[3];  C.l01_b = (const float*)d_in[4];
  C.cb1_w = (const float*)d_in[5];  C.cb1_b = (const float*)d_in[6];
  C.cc1_w = (const float*)d_in[7];  C.cc1_b = (const float*)d_in[8];
  C.r01_w = (const float*)d_in[9];  C.r01_b = (const float*)d_in[10];
  C.c1_w  = (const float*)d_in[11]; C.c1_b  = (const float*)d_in[12];
  C.l1_w  = (const float*)d_in[13]; C.l1_b  = (const float*)d_in[14];
  C.c2_w  = (const float*)d_in[15]; C.c2_b  = (const float*)d_in[16];
  C.ca_w  = (const float*)d_in[17]; C.ca_b  = (const float*)d_in[18];
  C.ra_w  = (const float*)d_in[19]; C.ra_b  = (const float*)d_in[20];
  C.ca2_w = (const float*)d_in[21]; C.ca2_b = (const float*)d_in[22];
  C.l02_w = (const float*)d_in[23]; C.l02_b = (const float*)d_in[24];
  C.cb2_w = (const float*)d_in[25]; C.cb2_b = (const float*)d_in[26];
  C.cc2_w = (const float*)d_in[27]; C.cc2_b = (const float*)d_in[28];
  C.r02_w = (const float*)d_in[29]; C.r02_b = (const float*)d_in[30];
  C.fl_w  = (const float*)d_in[31]; C.fl_b  = (const float*)d_in[32];
  C.out   = (float*)d_out;

  const int B = in_sizes[0] / 635;

  // ws layout: [fp32 region][bf16 activation pool]
  size_t actoff = ((size_t)F32_TOTAL * 4 + 255) & ~(size_t)255;
  int CB = 4096;
  if (CB > B) CB = B;
  while (CB > 256 && actoff + (size_t)ROWS_TOTAL * CB * 2 > ws_size) CB >>= 1;
  C.F = (float*)d_ws;
  C.A = (u16*)((char*)d_ws + actoff);
  C.CB = CB;

  C.b0g = 0;
  k0c<<<dim3(1), dim3(256), 0, stream>>>(C);

  const int bt64 = CB / 64, bt256 = (CB + 255) / 256;
  for (int b0 = 0; b0 < B; b0 += CB) {
    C.b0g = b0;
    k0t<<<dim3(bt64, 10),   dim3(256), 0, stream>>>(C);
    k1 <<<dim3(bt256, 10),  dim3(256), 0, stream>>>(C);
    k2 <<<dim3(bt256, 25),  dim3(256), 0, stream>>>(C);
    k3 <<<dim3(bt256, 30),  dim3(256), 0, stream>>>(C);
    k4 <<<dim3(bt256, 300), dim3(256), 0, stream>>>(C);
    k5 <<<dim3(bt256, 120), dim3(256), 0, stream>>>(C);
    k6 <<<dim3(bt64, 90),   dim3(256), 0, stream>>>(C);
    k7 <<<dim3(bt256, 375), dim3(256), 0, stream>>>(C);
    k8a<<<dim3(bt256, 20),  dim3(256), 0, stream>>>(C);
    k8b<<<dim3(bt256, 1),   dim3(256), 0, stream>>>(C);
  }
}

// Round 4
// 601.972 us; speedup vs baseline: 3.0714x; 2.0362x over previous
//
#include <hip/hip_runtime.h>

// Round 4: batch-major pipeline; tail (k8b) algebraically folded into k7/k8a
// via fp32 atomic partial sums; low-parallelism kernels split finer.

typedef unsigned short u16;

__device__ __forceinline__ float bf2f(u16 u) {
  return __uint_as_float(((unsigned)u) << 16);
}
__device__ __forceinline__ u16 f2bf(float f) {
  unsigned u = __float_as_uint(f);
  return (u16)((u + 0x7FFFu + ((u >> 16) & 1u)) >> 16);   // RNE
}

// ---- fp32 ws region offsets (floats) ----
#define OF_CS01   0        // 81
#define OF_CS1    81       // 30
#define OF_CSR    111      // 30
#define OF_CSAC   141      // 125
#define OF_CS02   266      // 10
#define OF_CSCC2  276      // 1
#define OF_L01T   277      // 127*81
#define OF_R01T   10564    // 127*81
#define OF_SWT    20851    // 81*60
#define OF_CB1T   25711    // 15*25
#define OF_C1T    26086    // 50*75
#define OF_C2T    29836    // 150*128 (o padded to 128)
#define OF_CAT    49036    // 75*128  (o padded to 128)
#define OF_SCT    58636    // 30*20
#define OF_CA2T   59236    // 250*25
#define F32_TOTAL 65486

// ---- activation pool row offsets (pitch = CB, bf16), lifetimes overlapped ----
#define R_XT   0      // 635   [K0T..K1]
#define R_XL   635    // 405   [K1..K2]
#define R_YA   1040   // 405   [K1..K3]
#define R_ZA   1445   // 2025  [K2..K3]
#define R_P    3470   // 1500  [K3..K4]
#define R_Q    4970   // 300   [K3..K4]
#define R_V    11250  // 7500  [K4..K6]
#define R_T    18750  // 9000  [K5..K6]
#define R_X2   0      // 11250 [K6..K7]  (reuses early region)
#define R_XJ   11250  // 3750  [K7..K8a] (left half only; reuses v)
#define ROWS_TOTAL 27750

struct Ctx {
  const float *x, *ca1_w, *ca1_b, *l01_b, *r01_b, *cb1_b, *cc1_w, *cc1_b;
  const float *c1_b, *l1_b, *c2_b, *ca_b, *ra_b, *ca2_b, *l02_b;
  const float *cb2_w, *cb2_b, *cc2_w, *cc2_b, *r02_b, *fl_w, *fl_b;
  const float *l01_w, *r01_w, *l1_w, *ra_w, *c1_w, *c2_w, *ca_w, *cb1_w;
  const float *l02_w, *r02_w, *ca2_w;
  float *F;         // fp32 derived-weight region (ws)
  float *zAcc;      // [CB]    fp32 atomic accumulator (ws)
  float *yAcc;      // [3][CB] fp32 atomic accumulator (ws)
  u16 *A;           // bf16 activation pool (ws)
  float *out;
  int CB;
  int b0g;
};

// ---------- K0C: constants + transposed weights. grid(32) ----------
__global__ __launch_bounds__(256) void k0c(Ctx C) {
  const int t0 = blockIdx.x * 256 + threadIdx.x;
  const int NT = 32 * 256;
  float* F = C.F;
  for (int k = t0; k < 277; k += NT) {
    float s = 0.f;
    if (k < 81)       { for (int i = 0; i < 127; ++i) s += C.l01_w[k * 127 + i]; F[OF_CS01 + k] = s; }
    else if (k < 111) { int j = k - 81;  for (int a = 0; a < 81; ++a) s += C.l1_w[j * 81 + a]; F[OF_CS1 + j] = s; }
    else if (k < 141) { int j = k - 111; for (int a = 0; a < 81; ++a) s += C.ra_w[j * 81 + a]; F[OF_CSR + j] = s; }
    else if (k < 266) { int o = k - 141; for (int i = 0; i < 75; ++i) s += C.ca_w[o * 75 + i]; F[OF_CSAC + o] = s; }
    else if (k < 276) { int q = k - 266; for (int j = 0; j < 30; ++j) s += C.l02_w[q * 30 + j]; F[OF_CS02 + q] = s; }
    else              { float ss = 0.f; for (int o = 0; o < 125; ++o) ss += C.cc2_w[o]; F[OF_CSCC2] = ss; }
  }
  for (int e = t0; e < 10287; e += NT) { int i = e / 81, a = e % 81; F[OF_L01T + e] = C.l01_w[a * 127 + i]; }
  for (int e = t0; e < 10287; e += NT) { int i = e / 81, a = e % 81; F[OF_R01T + e] = C.r01_w[a * 127 + i]; }
  for (int e = t0; e < 4860; e += NT)  { int a = e / 60, j2 = e % 60;
    F[OF_SWT + e] = (j2 < 30) ? C.l1_w[j2 * 81 + a] : C.ra_w[(j2 - 30) * 81 + a]; }
  for (int e = t0; e < 375; e += NT)   { int k = e / 25, c = e % 25; F[OF_CB1T + e] = C.cb1_w[c * 15 + k]; }
  for (int e = t0; e < 3750; e += NT)  { int k = e / 75, m = e % 75; F[OF_C1T + e] = C.c1_w[m * 50 + k]; }
  for (int e = t0; e < 19200; e += NT) { int k = e / 128, o = e % 128;
    F[OF_C2T + e] = (o < 125) ? C.c2_w[o * 150 + k] : 0.f; }
  for (int e = t0; e < 9600; e += NT)  { int k = e / 128, o = e % 128;
    F[OF_CAT + e] = (o < 125) ? C.ca_w[o * 75 + k] : 0.f; }
  for (int e = t0; e < 600; e += NT)   { int j = e / 20, q2 = e % 20;
    F[OF_SCT + e] = (q2 < 10) ? C.l02_w[q2 * 30 + j] : C.r02_w[(q2 - 10) * 30 + j]; }
  for (int e = t0; e < 6250; e += NT)  { int k = e / 25, c = e % 25; F[OF_CA2T + e] = C.ca2_w[c * 250 + k]; }
}

// ---------- K0T: transpose x -> xT[635][CB] bf16. grid (CB/64, 10) ----------
__global__ __launch_bounds__(256) void k0t(Ctx C) {
  __shared__ float tile[64][65];
  const int tid = threadIdx.x;
  const int b0 = blockIdx.x * 64;
  const int i0 = blockIdx.y * 64;
  for (int e = tid; e < 64 * 64; e += 256) {
    int s = e >> 6, ii = e & 63, gi = i0 + ii;
    if (gi < 635) tile[s][ii] = C.x[(size_t)(C.b0g + b0 + s) * 635 + gi];
  }
  __syncthreads();
  const int lane = tid & 63, wv = tid >> 6;
  u16* xT = C.A + (size_t)R_XT * C.CB;
#pragma unroll
  for (int k = 0; k < 16; ++k) {
    int r = wv * 16 + k, gi = i0 + r;
    if (gi < 635) xT[(size_t)gi * C.CB + b0 + lane] = f2bf(tile[lane][r]);
  }
}

// ---------- K1: XL = l01*x, yA = r01*x + r01_b. grid (CB/256, 30) ----------
__global__ __launch_bounds__(256) void k1(Ctx C) {
  const int col = blockIdx.x * 256 + threadIdx.x;
  if (col >= C.CB) return;
  const int g = blockIdx.y, type = g / 15, r = g % 15, h = r / 3, a0 = (r % 3) * 27;
  const u16* __restrict__ xT = C.A + (size_t)R_XT * C.CB;
  const float* __restrict__ wT = C.F + (type ? OF_R01T : OF_L01T) + a0;
  float acc[27];
#pragma unroll
  for (int a = 0; a < 27; ++a) acc[a] = 0.f;
  for (int i = 0; i < 127; ++i) {
    float xv = bf2f(xT[(size_t)(h * 127 + i) * C.CB + col]);
    const float* __restrict__ w = wT + i * 81;
#pragma unroll
    for (int a = 0; a < 27; ++a) acc[a] += w[a] * xv;
  }
  u16* dst = C.A + (size_t)(type ? R_YA : R_XL) * C.CB;
#pragma unroll
  for (int a = 0; a < 27; ++a) {
    float rr = acc[a] + (type ? C.r01_b[a0 + a] : 0.f);
    dst[(size_t)(h * 81 + a0 + a) * C.CB + col] = f2bf(rr);
  }
}

// ---------- K2: zA = relu(conv_ca1(XL) + ca1_b*S01 + l01_b). grid (CB/256, 75) ----------
__global__ __launch_bounds__(256) void k2(Ctx C) {
  const int col = blockIdx.x * 256 + threadIdx.x;
  if (col >= C.CB) return;
  const int g = blockIdx.y, c5 = g / 15, r = g % 15, h = r / 3, a0 = (r % 3) * 27;
  const u16* __restrict__ XL = C.A + (size_t)R_XL * C.CB;
  const float* __restrict__ F = C.F;
  float acc[27];
  float cb = C.ca1_b[c5];
#pragma unroll
  for (int a = 0; a < 27; ++a) acc[a] = cb * F[OF_CS01 + a0 + a] + C.l01_b[a0 + a];
  for (int dh = 0; dh < 3; ++dh) {
    int hp = h - 1 + dh;
    if (hp < 0 || hp > 4) continue;
    float w = C.ca1_w[c5 * 3 + dh];
#pragma unroll
    for (int a = 0; a < 27; ++a) acc[a] += w * bf2f(XL[(size_t)(hp * 81 + a0 + a) * C.CB + col]);
  }
  u16* zA = C.A + (size_t)R_ZA * C.CB;
#pragma unroll
  for (int a = 0; a < 27; ++a)
    zA[(size_t)((c5 * 5 + h) * 81 + a0 + a) * C.CB + col] = f2bf(fmaxf(acc[a], 0.f));
}

// ---------- K3: P = SW*zA, Q = SW*yA. grid (CB/256, 60) ----------
__global__ __launch_bounds__(256) void k3(Ctx C) {
  const int col = blockIdx.x * 256 + threadIdx.x;
  if (col >= C.CB) return;
  const int g = blockIdx.y, pair = g >> 1, j0 = (g & 1) * 30;
  const bool isP = (pair < 25);
  const u16* __restrict__ src = C.A + (size_t)(isP ? (R_ZA + pair * 81) : (R_YA + (pair - 25) * 81)) * C.CB;
  const float* __restrict__ SWT = C.F + OF_SWT + j0;
  float acc[30];
#pragma unroll
  for (int j = 0; j < 30; ++j) acc[j] = 0.f;
  for (int a = 0; a < 81; ++a) {
    float xv = bf2f(src[(size_t)a * C.CB + col]);
    const float* __restrict__ w = SWT + a * 60;
#pragma unroll
    for (int j = 0; j < 30; ++j) acc[j] += w[j] * xv;
  }
  u16* dst = C.A + (size_t)(isP ? (R_P + pair * 60) : (R_Q + (pair - 25) * 60)) * C.CB;
#pragma unroll
  for (int j = 0; j < 30; ++j) dst[(size_t)(j0 + j) * C.CB + col] = f2bf(acc[j]);
}

// ---------- K4: v = conv_cb1(P) + cc1_w*Q + bias. grid (CB/256, 300) ----------
__global__ __launch_bounds__(256) void k4(Ctx C) {
  const int col = blockIdx.x * 256 + threadIdx.x;
  if (col >= C.CB) return;
  const int g = blockIdx.y, h = g / 60, j2 = g % 60;
  const u16* __restrict__ Pb = C.A + (size_t)R_P * C.CB;
  const u16* __restrict__ Qb = C.A + (size_t)R_Q * C.CB;
  const float* __restrict__ F = C.F;
  float qv = bf2f(Qb[(size_t)(h * 60 + j2) * C.CB + col]);
  float sj = (j2 < 30) ? F[OF_CS1 + j2] : F[OF_CSR + (j2 - 30)];
  float acc[25];
#pragma unroll
  for (int c = 0; c < 25; ++c) acc[c] = C.cc1_w[c] * qv + (C.cb1_b[c] + C.cc1_b[c]) * sj;
  for (int k = 0; k < 15; ++k) {
    int c5 = k / 3, dh = k % 3, hp = h - 1 + dh;
    if (hp < 0 || hp > 4) continue;
    float xv = bf2f(Pb[(size_t)((c5 * 5 + hp) * 60 + j2) * C.CB + col]);
    const float* __restrict__ w = F + OF_CB1T + k * 25;
#pragma unroll
    for (int c = 0; c < 25; ++c) acc[c] += w[c] * xv;
  }
  u16* vb = C.A + (size_t)R_V * C.CB;
#pragma unroll
  for (int c = 0; c < 25; ++c)
    vb[(size_t)((c * 5 + h) * 60 + j2) * C.CB + col] = f2bf(acc[c]);
}

// ---------- K5: t = relu(conv_c1(vL) + c1_b*S1 + l1_b). grid (CB/256, 120) ----------
__global__ __launch_bounds__(256) void k5(Ctx C) {
  const int col = blockIdx.x * 256 + threadIdx.x;
  if (col >= C.CB) return;
  const int g = blockIdx.y, h4 = g / 30, j = g % 30;
  const u16* __restrict__ vb = C.A + (size_t)R_V * C.CB;
  const float* __restrict__ F = C.F;
  float acc[75];
#pragma unroll
  for (int m = 0; m < 75; ++m) acc[m] = 0.f;
  for (int k = 0; k < 50; ++k) {
    int c = k >> 1, dc = k & 1;
    float xv = bf2f(vb[(size_t)((c * 5 + h4 + dc) * 60 + j) * C.CB + col]);
    const float* __restrict__ w = F + OF_C1T + k * 75;
#pragma unroll
    for (int m = 0; m < 75; ++m) acc[m] += w[m] * xv;
  }
  u16* tb = C.A + (size_t)R_T * C.CB;
  float s1 = F[OF_CS1 + j];
#pragma unroll
  for (int m = 0; m < 75; ++m) {
    float r = acc[m] + C.c1_b[m] * s1 + C.l1_b[j];
    tb[(size_t)((m * 4 + h4) * 30 + j) * C.CB + col] = f2bf(fmaxf(r, 0.f));
  }
}

// ---------- K6: x2 = conv_c2(t) + conv_ca(vR) + bias. grid (CB/64, 90) ----------
__global__ __launch_bounds__(256) void k6(Ctx C) {
  const int tid = threadIdx.x;
  const int col = blockIdx.x * 64 + (tid & 63);
  const int ow = __builtin_amdgcn_readfirstlane(tid >> 6) * 32;
  const int g = blockIdx.y, h3 = g / 30, j = g % 30;
  const u16* __restrict__ tb = C.A + (size_t)R_T * C.CB;
  const u16* __restrict__ vb = C.A + (size_t)R_V * C.CB;
  const float* __restrict__ F = C.F;
  float acc[32];
#pragma unroll
  for (int i = 0; i < 32; ++i) acc[i] = 0.f;
  for (int k = 0; k < 150; ++k) {
    int m = k >> 1, dc = k & 1;
    float xv = bf2f(tb[(size_t)((m * 4 + h3 + dc) * 30 + j) * C.CB + col]);
    const float* __restrict__ w = F + OF_C2T + k * 128 + ow;
#pragma unroll
    for (int i = 0; i < 32; ++i) acc[i] += w[i] * xv;
  }
  for (int k = 0; k < 75; ++k) {
    int c = k / 3, dc3 = k % 3;
    float xv = bf2f(vb[(size_t)((c * 5 + h3 + dc3) * 60 + 30 + j) * C.CB + col]);
    const float* __restrict__ w = F + OF_CAT + k * 128 + ow;
#pragma unroll
    for (int i = 0; i < 32; ++i) acc[i] += w[i] * xv;
  }
  u16* x2b = C.A + (size_t)R_X2 * C.CB;
  float rbj = C.ra_b[j];
#pragma unroll
  for (int i = 0; i < 32; ++i) {
    int o = ow + i;
    if (o < 125) {
      float r = acc[i] + C.c2_b[o] + C.ca_b[o] + rbj * F[OF_CSAC + o];
      x2b[(size_t)((o * 3 + h3) * 30 + j) * C.CB + col] = f2bf(r);
    }
  }
}

// ---------- K7: XJ_left = SC_l * x2; fold right half into yAcc. grid (CB/256, 375) ----------
__global__ __launch_bounds__(256) void k7(Ctx C) {
  const int col = blockIdx.x * 256 + threadIdx.x;
  if (col >= C.CB) return;
  const int g = blockIdx.y;               // g = o*3 + h3
  const int o = g / 3, h3 = g % 3;
  const u16* __restrict__ x2b = C.A + (size_t)R_X2 * C.CB;
  const float* __restrict__ SCT = C.F + OF_SCT;
  float acc[20];
#pragma unroll
  for (int q = 0; q < 20; ++q) acc[q] = 0.f;
  for (int j = 0; j < 30; ++j) {
    float xv = bf2f(x2b[(size_t)(g * 30 + j) * C.CB + col]);
    const float* __restrict__ w = SCT + j * 20;
#pragma unroll
    for (int q = 0; q < 20; ++q) acc[q] += w[q] * xv;
  }
  u16* XJ = C.A + (size_t)R_XJ * C.CB;   // pitch 10 rows per g
#pragma unroll
  for (int q = 0; q < 10; ++q) XJ[(size_t)(g * 10 + q) * C.CB + col] = f2bf(acc[q]);
  float s = 0.f;
#pragma unroll
  for (int q = 0; q < 10; ++q) s += C.fl_w[q] * acc[10 + q];
  atomicAdd(&C.yAcc[(size_t)h3 * C.CB + col], C.cc2_w[o] * s);
}

// ---------- K8a: zC in regs; fold cb2+fl into zAcc. grid (CB/256, 20) ----------
__global__ __launch_bounds__(256) void k8a(Ctx C) {
  const int col = blockIdx.x * 256 + threadIdx.x;
  if (col >= C.CB) return;
  const int g = blockIdx.y, hh = g / 10, q = g % 10;
  const u16* __restrict__ XJ = C.A + (size_t)R_XJ * C.CB;
  const float* __restrict__ F = C.F;
  float acc[25];
#pragma unroll
  for (int c = 0; c < 25; ++c) acc[c] = 0.f;
  for (int k = 0; k < 250; ++k) {
    int o = k >> 1, dh = k & 1;
    float xv = bf2f(XJ[(size_t)((o * 3 + hh + dh) * 10 + q) * C.CB + col]);
    const float* __restrict__ w = F + OF_CA2T + k * 25;
#pragma unroll
    for (int c = 0; c < 25; ++c) acc[c] += w[c] * xv;
  }
  float s02 = F[OF_CS02 + q];
  float part = 0.f;
#pragma unroll
  for (int c = 0; c < 25; ++c) {
    float zc = fmaxf(acc[c] + C.ca2_b[c] * s02 + C.l02_b[q], 0.f);
    part += C.cb2_w[c * 2 + hh] * zc;
  }
  atomicAdd(&C.zAcc[col], C.fl_w[q] * part);
}

// ---------- K8c: out = const + zAcc + yAcc[h]. grid (CB/256, 1) ----------
__global__ __launch_bounds__(256) void k8c(Ctx C) {
  const int col = blockIdx.x * 256 + threadIdx.x;
  if (col >= C.CB) return;
  float scc2 = C.F[OF_CSCC2];
  float cst = C.fl_b[0];
#pragma unroll
  for (int q = 0; q < 10; ++q)
    cst += C.fl_w[q] * (C.cb2_b[0] + C.r02_b[q] * scc2 + C.cc2_b[0]);
  float za = C.zAcc[col];
#pragma unroll
  for (int h = 0; h < 3; ++h)
    C.out[(size_t)(C.b0g + col) * 3 + h] = cst + za + C.yAcc[(size_t)h * C.CB + col];
}

extern "C" void kernel_launch(void* const* d_in, const int* in_sizes, int n_in,
                              void* d_out, int out_size, void* d_ws, size_t ws_size,
                              hipStream_t stream) {
  (void)n_in; (void)out_size;
  Ctx C;
  C.x     = (const float*)d_in[0];
  C.ca1_w = (const float*)d_in[1];  C.ca1_b = (const float*)d_in[2];
  C.l01_w = (const float*)d_in[3];  C.l01_b = (const float*)d_in[4];
  C.cb1_w = (const float*)d_in[5];  C.cb1_b = (const float*)d_in[6];
  C.cc1_w = (const float*)d_in[7];  C.cc1_b = (const float*)d_in[8];
  C.r01_w = (const float*)d_in[9];  C.r01_b = (const float*)d_in[10];
  C.c1_w  = (const float*)d_in[11]; C.c1_b  = (const float*)d_in[12];
  C.l1_w  = (const float*)d_in[13]; C.l1_b  = (const float*)d_in[14];
  C.c2_w  = (const float*)d_in[15]; C.c2_b  = (const float*)d_in[16];
  C.ca_w  = (const float*)d_in[17]; C.ca_b  = (const float*)d_in[18];
  C.ra_w  = (const float*)d_in[19]; C.ra_b  = (const float*)d_in[20];
  C.ca2_w = (const float*)d_in[21]; C.ca2_b = (const float*)d_in[22];
  C.l02_w = (const float*)d_in[23]; C.l02_b = (const float*)d_in[24];
  C.cb2_w = (const float*)d_in[25]; C.cb2_b = (const float*)d_in[26];
  C.cc2_w = (const float*)d_in[27]; C.cc2_b = (const float*)d_in[28];
  C.r02_w = (const float*)d_in[29]; C.r02_b = (const float*)d_in[30];
  C.fl_w  = (const float*)d_in[31]; C.fl_b  = (const float*)d_in[32];
  C.out   = (float*)d_out;

  const int B = in_sizes[0] / 635;

  // ws layout: [fp32 weights][zAcc|yAcc fp32][bf16 activation pool]
  int CB = 4096;
  if (CB > B) CB = B;
  size_t accoff, actoff;
  for (;;) {
    accoff = ((size_t)F32_TOTAL * 4 + 255) & ~(size_t)255;
    actoff = (accoff + (size_t)4 * CB * 4 + 255) & ~(size_t)255;
    if (CB <= 256 || actoff + (size_t)ROWS_TOTAL * CB * 2 <= ws_size) break;
    CB >>= 1;
  }
  C.F = (float*)d_ws;
  C.zAcc = (float*)((char*)d_ws + accoff);
  C.yAcc = C.zAcc + CB;
  C.A = (u16*)((char*)d_ws + actoff);
  C.CB = CB;

  C.b0g = 0;
  k0c<<<dim3(32), dim3(256), 0, stream>>>(C);

  const int bt64 = CB / 64, bt256 = (CB + 255) / 256;
  for (int b0 = 0; b0 < B; b0 += CB) {
    C.b0g = b0;
    hipMemsetAsync(C.zAcc, 0, (size_t)4 * CB * sizeof(float), stream);
    k0t<<<dim3(bt64, 10),   dim3(256), 0, stream>>>(C);
    k1 <<<dim3(bt256, 30),  dim3(256), 0, stream>>>(C);
    k2 <<<dim3(bt256, 75),  dim3(256), 0, stream>>>(C);
    k3 <<<dim3(bt256, 60),  dim3(256), 0, stream>>>(C);
    k4 <<<dim3(bt256, 300), dim3(256), 0, stream>>>(C);
    k5 <<<dim3(bt256, 120), dim3(256), 0, stream>>>(C);
    k6 <<<dim3(bt64, 90),   dim3(256), 0, stream>>>(C);
    k7 <<<dim3(bt256, 375), dim3(256), 0, stream>>>(C);
    k8a<<<dim3(bt256, 20),  dim3(256), 0, stream>>>(C);
    k8c<<<dim3(bt256, 1),   dim3(256), 0, stream>>>(C);
  }
}